// Round 5
// baseline (7299.718 us; speedup 1.0000x reference)
//
#include <hip/hip_runtime.h>
#include <math.h>

#define BB 16
#define TT 1024
#define FF 128
#define RR 2048
#define HALFR 1024
#define NBLK 128
#define NTHR 512

typedef __attribute__((ext_vector_type(4))) unsigned int u32x4;
typedef __attribute__((ext_vector_type(8))) short bf16x8;
typedef __attribute__((ext_vector_type(4))) float f32x4;

// ---- coherent (IC-level) memory ops: bypass L1/L2, no fences needed ----
__device__ __forceinline__ u32x4 ldg_sc4u(const unsigned* base, unsigned voff) {
    u32x4 r;
    asm volatile("global_load_dwordx4 %0, %1, %2 sc0 sc1"
                 : "=v"(r) : "v"(voff), "s"(base) : "memory");
    return r;
}
__device__ __forceinline__ unsigned ldg_sc1u(const unsigned* base, unsigned voff) {
    unsigned r;
    asm volatile("global_load_dword %0, %1, %2 sc0 sc1"
                 : "=v"(r) : "v"(voff), "s"(base) : "memory");
    return r;
}
__device__ __forceinline__ void stg_sc1u(unsigned* base, unsigned voff, unsigned v) {
    asm volatile("global_store_dword %0, %1, %2 sc0 sc1"
                 :: "v"(voff), "v"(v), "s"(base) : "memory");
}
__device__ __forceinline__ void wait_vm0() {
    asm volatile("s_waitcnt vmcnt(0)" ::: "memory");
}

__device__ __forceinline__ bf16x8 as_bf16x8(u32x4 u) {
    union { u32x4 u4; bf16x8 b8; } c; c.u4 = u; return c.b8;
}

// split fp32 v -> (hh bits, hl bits), each a bf16 pattern; RTN via +0x8000.
__device__ __forceinline__ void split_bf16(float v, unsigned& hh, unsigned& hl) {
    unsigned uh = (__float_as_uint(v) + 0x8000u) & 0xFFFF0000u;
    float rem = v - __uint_as_float(uh);
    unsigned ul = (__float_as_uint(rem) + 0x8000u) & 0xFFFF0000u;
    hh = uh >> 16; hl = ul >> 16;
}
// pack fp32 into one u32: low16 = bf16(hi part), high16 = bf16(residual)
__device__ __forceinline__ unsigned pack_h(float v) {
    unsigned hh, hl; split_bf16(v, hh, hl);
    return (hl << 16) | hh;
}
__device__ __forceinline__ float unpack_h(unsigned p) {
    return __uint_as_float(p << 16) + __uint_as_float(p & 0xFFFF0000u);
}

// ---------------- init: packed h0 + barrier words ----------------
__global__ void init_state_kernel(unsigned* __restrict__ h, const float* __restrict__ start,
                                  unsigned* __restrict__ bar) {
    int idx = blockIdx.x * blockDim.x + threadIdx.x;
    if (idx < BB * RR) h[idx] = pack_h(start[idx & (RR - 1)]);
    if (idx < 2048) bar[idx] = 0u;
}

// ---------------- persistent MFMA ESN kernel ----------------
// R15: the per-step op IS a GEMM (y[16,2048] = h[16,2048]W^T + x[16,128]Win^T)
// — move it to the matrix cores. R10-R14 all plateaued at 6.3-7.6us because
// the VALU dot-product structure costs 512 FMA/lane + ~3us of DS-pipe (W
// b128 reads + shuffle folds) per step, regardless of arrangement.
//  - fp32 precision via split-bf16: operand = hi(bf16,RTN) + lo(bf16 of
//    residual); y = Wh*hh + Wh*hl + Wl*hh in 3 fp32-accum MFMA chains
//    (product rel err ~2^-15; contractive recurrence keeps state err <5e-4).
//  - h stored PACKED (hi,lo) in one u32 (same 4B/elem): per-step fragment
//    prep = pure bit-ops (no cvt), epilogue packs once.
//  - 128 blocks x 16 cols; 8 waves split K=2048 into 256-chunks; W frags
//    (16 cols x 256 k as bf16 hi+lo) live in 64 VGPRs, converted ONCE.
//  - mfma_f32_16x16x32_bf16: A[m=lane&15][k=8*(lane>>4)+e] (h), B[k][n]
//    mirrored (W); D: col=lane&15, row=(lane>>4)*4+reg (m89-verified).
//  - input proj fused as extra K-segment on waves 0-3 of blocks r0<HALFR.
//  - cross-wave reduce: 8 partial 16x16 tiles via 8KB LDS; epilogue on
//    tid<256 (one elem each: m=tid>>4, n=tid&15).
//  - h path mechanics (sc0sc1 loads up-front, vmcnt0+sched_barrier, sc
//    store, drain before barrier) and two-level all-relaxed barrier are the
//    proven R10/R13 forms, retuned for 128 blocks (16 groups x 8).
__global__ __launch_bounds__(NTHR, 2) void esn_mfma(
    const float* __restrict__ inputs,   // [B,T,F]
    const float* __restrict__ Win,      // [R,F]
    const float* __restrict__ Wrec,     // [R,R]
    const float* __restrict__ bias,     // [R]
    unsigned* __restrict__ hA,          // [B,R] packed
    unsigned* __restrict__ hB,          // [B,R] packed
    float* __restrict__ out,            // [B,T,HALFR]
    unsigned* __restrict__ bar)
{
    __shared__ __align__(16) float sRed[8 * 256];   // 8 KB

    const int tid  = threadIdx.x;
    const int lane = tid & 63;
    const int wave = tid >> 6;          // 0..7 : K-chunk owner (k in [wave*256, +256))
    const int r0   = blockIdx.x * 16;   // this block's 16 output columns
    const int col  = lane & 15;         // B-operand n / A-operand m (batch)
    const int kg   = lane >> 4;         // k-group 0..3 within each 32-chunk
    const int ksb  = wave * 256;
    const bool projb = (r0 < HALFR);

    // ---- W_rec -> register fragments (once; reused 1024 steps) ----
    bf16x8 Wh[8], Wl[8];
#pragma unroll
    for (int s = 0; s < 8; ++s) {
        const float* wp = Wrec + (size_t)(r0 + col) * RR + ksb + s * 32 + kg * 8;
        const float4 w0 = *(const float4*)wp;
        const float4 w1 = *(const float4*)(wp + 4);
        const float wv[8] = {w0.x, w0.y, w0.z, w0.w, w1.x, w1.y, w1.z, w1.w};
        unsigned hh[8], hl[8];
#pragma unroll
        for (int e = 0; e < 8; ++e) split_bf16(wv[e], hh[e], hl[e]);
        u32x4 ph = { hh[0] | (hh[1] << 16), hh[2] | (hh[3] << 16),
                     hh[4] | (hh[5] << 16), hh[6] | (hh[7] << 16) };
        u32x4 pl = { hl[0] | (hl[1] << 16), hl[2] | (hl[3] << 16),
                     hl[4] | (hl[5] << 16), hl[6] | (hl[7] << 16) };
        Wh[s] = as_bf16x8(ph);
        Wl[s] = as_bf16x8(pl);
    }

    // ---- Win -> register fragments (waves 0-3 of proj blocks; K=128) ----
    bf16x8 Ih = {0,0,0,0,0,0,0,0}, Il = {0,0,0,0,0,0,0,0};
    if (projb && wave < 4) {
        const float* ip = Win + (size_t)(r0 + col) * FF + wave * 32 + kg * 8;
        const float4 w0 = *(const float4*)ip;
        const float4 w1 = *(const float4*)(ip + 4);
        const float wv[8] = {w0.x, w0.y, w0.z, w0.w, w1.x, w1.y, w1.z, w1.w};
        unsigned hh[8], hl[8];
#pragma unroll
        for (int e = 0; e < 8; ++e) split_bf16(wv[e], hh[e], hl[e]);
        u32x4 ph = { hh[0] | (hh[1] << 16), hh[2] | (hh[3] << 16),
                     hh[4] | (hh[5] << 16), hh[6] | (hh[7] << 16) };
        u32x4 pl = { hl[0] | (hl[1] << 16), hl[2] | (hl[3] << 16),
                     hl[4] | (hl[5] << 16), hl[6] | (hl[7] << 16) };
        Ih = as_bf16x8(ph);
        Il = as_bf16x8(pl);
    }

    // ---- h-load byte offsets: batch=col, k = ksb + s*32 + kg*8 ----
    unsigned voffH[8][2];
#pragma unroll
    for (int s = 0; s < 8; ++s) {
        const unsigned base = (unsigned)(((col * RR) + ksb + s * 32 + kg * 8) * 4);
        voffH[s][0] = base;
        voffH[s][1] = base + 16;
    }
    // per-lane x base (proj waves): batch=col, f = wave*32 + kg*8
    const size_t xbase = (size_t)col * TT * FF + wave * 32 + kg * 8;

    // ---- epilogue mapping: tid<256 -> elem (m=tid>>4, n=tid&15) ----
    const int mE = tid >> 4;            // batch (for tid<256)
    const int nE = tid & 15;            // col within block
    const int eBc = (tid < 256) ? mE : 0;
    const float myBias = bias[r0 + nE];
    const unsigned eOff = (unsigned)((eBc * RR + r0 + nE) * 4);

    // ---- two-level barrier state: 16 groups x 8 blocks ----
    const unsigned g = blockIdx.x & 15u;
    unsigned* grpCnt      = bar + g * 32;
    unsigned* masterCnt   = bar + 16 * 32;
    unsigned* masterEpoch = bar + 17 * 32;
    unsigned* grpEpoch    = bar + (18 + g) * 32;

    for (int t = 0; t < TT; ++t) {
        const unsigned* hc = (t & 1) ? hB : hA;
        unsigned*       hn = (t & 1) ? hA : hB;

        // 1) Issue all coherent h loads up front (16 + 1 in flight).
        u32x4 hld[16];
#pragma unroll
        for (int s = 0; s < 8; ++s) {
            hld[2 * s]     = ldg_sc4u(hc, voffH[s][0]);
            hld[2 * s + 1] = ldg_sc4u(hc, voffH[s][1]);
        }
        const unsigned holdu = ldg_sc1u(hc, eOff);

        // 2) x loads (normal cached; compiler waits are conservative-safe
        //    in the presence of our asm loads) overlap the IC latency.
        float4 x0, x1;
        if (projb && wave < 4) {
            const float* xp = inputs + xbase + (size_t)t * FF;
            x0 = *(const float4*)xp;
            x1 = *(const float4*)(xp + 4);
        }

        // 3) Drain, pin ordering (rule #18), then MFMA.
        wait_vm0();
        __builtin_amdgcn_sched_barrier(0);

        f32x4 accA = {0.f, 0.f, 0.f, 0.f};
        f32x4 accB = {0.f, 0.f, 0.f, 0.f};
        f32x4 accC = {0.f, 0.f, 0.f, 0.f};
#pragma unroll
        for (int s = 0; s < 8; ++s) {
            const u32x4 pa = hld[2 * s];
            const u32x4 pb = hld[2 * s + 1];
            u32x4 ahh = { (pa.x & 0xFFFFu) | (pa.y << 16),
                          (pa.z & 0xFFFFu) | (pa.w << 16),
                          (pb.x & 0xFFFFu) | (pb.y << 16),
                          (pb.z & 0xFFFFu) | (pb.w << 16) };
            u32x4 ahl = { (pa.x >> 16) | (pa.y & 0xFFFF0000u),
                          (pa.z >> 16) | (pa.w & 0xFFFF0000u),
                          (pb.x >> 16) | (pb.y & 0xFFFF0000u),
                          (pb.z >> 16) | (pb.w & 0xFFFF0000u) };
            const bf16x8 Ah = as_bf16x8(ahh);
            const bf16x8 Al = as_bf16x8(ahl);
            accA = __builtin_amdgcn_mfma_f32_16x16x32_bf16(Ah, Wh[s], accA, 0, 0, 0);
            accB = __builtin_amdgcn_mfma_f32_16x16x32_bf16(Al, Wh[s], accB, 0, 0, 0);
            accC = __builtin_amdgcn_mfma_f32_16x16x32_bf16(Ah, Wl[s], accC, 0, 0, 0);
        }
        if (projb && wave < 4) {
            const float xv[8] = {x0.x, x0.y, x0.z, x0.w, x1.x, x1.y, x1.z, x1.w};
            unsigned hh[8], hl[8];
#pragma unroll
            for (int e = 0; e < 8; ++e) split_bf16(xv[e], hh[e], hl[e]);
            u32x4 ph = { hh[0] | (hh[1] << 16), hh[2] | (hh[3] << 16),
                         hh[4] | (hh[5] << 16), hh[6] | (hh[7] << 16) };
            u32x4 pl = { hl[0] | (hl[1] << 16), hl[2] | (hl[3] << 16),
                         hl[4] | (hl[5] << 16), hl[6] | (hl[7] << 16) };
            const bf16x8 Axh = as_bf16x8(ph);
            const bf16x8 Axl = as_bf16x8(pl);
            accA = __builtin_amdgcn_mfma_f32_16x16x32_bf16(Axh, Ih, accA, 0, 0, 0);
            accB = __builtin_amdgcn_mfma_f32_16x16x32_bf16(Axl, Ih, accB, 0, 0, 0);
            accC = __builtin_amdgcn_mfma_f32_16x16x32_bf16(Axh, Il, accC, 0, 0, 0);
        }
        const f32x4 acc = accA + accB + accC;

        // 4) Cross-wave reduce: 8 partial 16x16 tiles -> LDS -> tid<256 sums.
        *(f32x4*)&sRed[wave * 256 + lane * 4] = acc;
        __syncthreads();
        if (tid < 256) {
            const int ridx = ((mE >> 2) * 16 + nE) * 4 + (mE & 3);
            float val = 0.f;
#pragma unroll
            for (int w = 0; w < 8; ++w) val += sRed[w * 256 + ridx];
            const float pre  = val + myBias;
            const float hold = unpack_h(holdu);
            const float vnew = 0.05f * hold + 0.95f * tanhf(pre);
            stg_sc1u(hn, eOff, pack_h(vnew));
            if (r0 >= HALFR)
                out[((size_t)mE * TT + t) * HALFR + (r0 + nE - HALFR)] = vnew;
        }

        // 5) Drain stores, block-sync, two-level all-relaxed grid barrier.
        wait_vm0();
        __syncthreads();
        if (tid == 0) {
            const unsigned tgt = (unsigned)(t + 1);
            const unsigned old = __hip_atomic_fetch_add(grpCnt, 1u, __ATOMIC_RELAXED,
                                                        __HIP_MEMORY_SCOPE_AGENT);
            if (old == tgt * 8u - 1u) {                    // last arriver in group of 8
                const unsigned mo = __hip_atomic_fetch_add(masterCnt, 1u, __ATOMIC_RELAXED,
                                                           __HIP_MEMORY_SCOPE_AGENT);
                if (mo == tgt * 16u - 1u) {                // last of 16 groups
                    __hip_atomic_store(masterEpoch, tgt, __ATOMIC_RELAXED,
                                       __HIP_MEMORY_SCOPE_AGENT);
                } else {
                    while (__hip_atomic_load(masterEpoch, __ATOMIC_RELAXED,
                                             __HIP_MEMORY_SCOPE_AGENT) < tgt)
                        __builtin_amdgcn_s_sleep(2);
                }
                __hip_atomic_store(grpEpoch, tgt, __ATOMIC_RELAXED,
                                   __HIP_MEMORY_SCOPE_AGENT);
            } else {
                while (__hip_atomic_load(grpEpoch, __ATOMIC_RELAXED,
                                         __HIP_MEMORY_SCOPE_AGENT) < tgt)
                    __builtin_amdgcn_s_sleep(2);
            }
        }
        __syncthreads();
    }
}

// ---------------- fallback path (proven R1): fp32, 1024 launches ----------------

__global__ void init_h_kernel(float* __restrict__ h, const float* __restrict__ start) {
    int idx = blockIdx.x * blockDim.x + threadIdx.x;
    if (idx < BB * RR) h[idx] = start[idx & (RR - 1)];
}

__global__ __launch_bounds__(512, 2) void step_kernel(
    const float* __restrict__ inputs, const float* __restrict__ Win,
    const float* __restrict__ Wrec, const float* __restrict__ bias,
    const float* __restrict__ h_cur, float* __restrict__ h_next,
    float* __restrict__ out, int t)
{
    const int tid  = threadIdx.x;
    const int wave = tid >> 6;
    const int half = (tid >> 5) & 1;
    const int kl   = tid & 31;
    const int b    = wave * 2 + half;
    const int r0   = blockIdx.x * 8;

    float acc[8];
#pragma unroll
    for (int r = 0; r < 8; ++r) acc[r] = 0.0f;

    if (r0 < HALFR) {
        const float4 in4 = *reinterpret_cast<const float4*>(
            inputs + ((size_t)b * TT + t) * FF + kl * 4);
#pragma unroll
        for (int r = 0; r < 8; ++r) {
            const float4 w4 = *reinterpret_cast<const float4*>(
                Win + (size_t)(r0 + r) * FF + kl * 4);
            acc[r] += in4.x * w4.x + in4.y * w4.y + in4.z * w4.z + in4.w * w4.w;
        }
    }

    const float* hb = h_cur + (size_t)b * RR;
#pragma unroll 2
    for (int j = 0; j < 16; ++j) {
        const int k = kl * 4 + j * 128;
        const float4 h4 = *reinterpret_cast<const float4*>(hb + k);
#pragma unroll
        for (int r = 0; r < 8; ++r) {
            const float4 w4 = *reinterpret_cast<const float4*>(
                Wrec + (size_t)(r0 + r) * RR + k);
            acc[r] = fmaf(h4.x, w4.x, acc[r]);
            acc[r] = fmaf(h4.y, w4.y, acc[r]);
            acc[r] = fmaf(h4.z, w4.z, acc[r]);
            acc[r] = fmaf(h4.w, w4.w, acc[r]);
        }
    }

#pragma unroll
    for (int r = 0; r < 8; ++r) {
        float v = acc[r];
        v += __shfl_xor(v, 1);  v += __shfl_xor(v, 2);
        v += __shfl_xor(v, 4);  v += __shfl_xor(v, 8);
        v += __shfl_xor(v, 16);
        acc[r] = v;
    }

    __shared__ float red[BB][8];
    if (kl == 0) {
#pragma unroll
        for (int r = 0; r < 8; ++r) red[b][r] = acc[r];
    }
    __syncthreads();

    if (tid < BB * 8) {
        const int rr = tid & 7, bb = tid >> 3;
        const int r  = r0 + rr;
        const float pre = red[bb][rr] + bias[r];
        const float h_old = h_cur[(size_t)bb * RR + r];
        const float hn = 0.05f * h_old + 0.95f * tanhf(pre);
        h_next[(size_t)bb * RR + r] = hn;
        if (r0 >= HALFR) out[((size_t)bb * TT + t) * HALFR + (r - HALFR)] = hn;
    }
}

// ---------------- launch ----------------

extern "C" void kernel_launch(void* const* d_in, const int* in_sizes, int n_in,
                              void* d_out, int out_size, void* d_ws, size_t ws_size,
                              hipStream_t stream) {
    const float* inputs = (const float*)d_in[0];   // [B,T,F]
    const float* Win    = (const float*)d_in[1];   // [R,F]
    const float* Wrec   = (const float*)d_in[2];   // [R,R]
    const float* bias   = (const float*)d_in[3];   // [R]
    const float* start  = (const float*)d_in[4];   // [R]
    float* out = (float*)d_out;                    // [B,T,HALFR]

    unsigned* hA = (unsigned*)d_ws;                // [B,R] packed bf16-pair
    unsigned* hB = hA + (size_t)BB * RR;           // [B,R] packed
    unsigned* bar = hB + (size_t)BB * RR;
    const size_t need = (size_t)BB * RR * 4 * 2 + 8192;

    if (ws_size >= need) {
        init_state_kernel<<<64, 512, 0, stream>>>(hA, start, bar);
        void* args[] = { (void*)&inputs, (void*)&Win, (void*)&Wrec, (void*)&bias,
                         (void*)&hA, (void*)&hB, (void*)&out, (void*)&bar };
        hipLaunchCooperativeKernel((void*)esn_mfma, dim3(NBLK), dim3(NTHR),
                                   args, 0, stream);
    } else {
        float* fA = (float*)d_ws;
        float* fB = fA + (size_t)BB * RR;
        init_h_kernel<<<(BB * RR + 255) / 256, 256, 0, stream>>>(fA, start);
        for (int t = 0; t < TT; ++t) {
            const float* hcur = (t & 1) ? fB : fA;
            float*       hnxt = (t & 1) ? fA : fB;
            step_kernel<<<256, 512, 0, stream>>>(inputs, Win, Wrec, bias, hcur, hnxt, out, t);
        }
    }
}